// Round 1
// baseline (64.954 us; speedup 1.0000x reference)
//
#include <hip/hip_runtime.h>

#define NT 100
#define NSTEPS 99

static __device__ __forceinline__ float fast_exp2(float x) {
#if __has_builtin(__builtin_amdgcn_exp2f)
    return __builtin_amdgcn_exp2f(x);
#else
    return exp2f(x);
#endif
}
static __device__ __forceinline__ float fast_rcp(float x) {
#if __has_builtin(__builtin_amdgcn_rcpf)
    return __builtin_amdgcn_rcpf(x);
#else
    return 1.0f / x;
#endif
}

// One thread = one sample; serial loop over the 99 EM steps.
// out layout: z_t [100*n] floats, then kld [n] floats.
__global__ __launch_bounds__(256, 4)
void sde_kernel(const float* __restrict__ z0_raw,
                const float* __restrict__ dW_raw,
                const float* __restrict__ W1,
                const float* __restrict__ b1,
                const float* __restrict__ wt,
                const float* __restrict__ W2,
                const float* __restrict__ b2,
                float* __restrict__ out,
                int n)
{
    int i = blockIdx.x * blockDim.x + threadIdx.x;
    if (i >= n) return;

    // Pre-scale weights by K = 2*log2(e) so tanh(x) = 1 - 2*rcp(1 + exp2(x*K))
    const float K = 2.88539008177792681f;
    float aK[8], wtK[8], b1K[8], mW2[8];
    float S = b2[0];
#pragma unroll
    for (int j = 0; j < 8; ++j) {
        aK[j]  = W1[j] * K;
        wtK[j] = wt[j] * K;
        b1K[j] = b1[j] * K;
        float w = W2[j];
        S += w;               // f = S + sum_j r_j * (-2*W2_j), with r_j = rcp(1+e^{2x})
        mW2[j] = -2.0f * w;
    }

    const float dt  = 3.0f / 99.0f;                 // linspace(0,3,100) step (uniform to ulp)
    const float csq = 0.24618298195866545f;         // sqrt(2)*sqrt(dt) = sqrt(2*dt)
    const float qc  = 0.25f * dt;                   // dt*0.5 * (1/2 from u = u'/sqrt(2))

    float z   = z0_raw[i] * 3.0f;
    float kld = 0.0f;
    out[i] = z;                                     // z_t[0]

    const float* dwp = dW_raw + i;
    float*       zp  = out + (size_t)n + i;

    float dwr = *dwp;                               // dW for step 0

    for (int k = 0; k < NSTEPS; ++k) {
        // prefetch next step's noise (uniform branch; hides HBM latency under the exp chain)
        float dwr_next = 0.0f;
        if (k + 1 < NSTEPS) dwr_next = dwp[(size_t)(k + 1) * n];

        float t0  = (float)k * dt;
        float acc = S;
#pragma unroll
        for (int j = 0; j < 8; ++j) {
            float pre = fmaf(z, aK[j], fmaf(t0, wtK[j], b1K[j]));  // K-scaled preactivation
            float y   = fast_exp2(pre);                             // e^{2x}
            float r   = fast_rcp(y + 1.0f);                         // 1/(1+e^{2x})
            acc = fmaf(r, mW2[j], acc);                             // += (1-2r)*W2 folded
        }
        float f    = acc;
        float znew = fmaf(dwr, csq, fmaf(f, dt, z));   // z + f*dt + sqrt(2)*sqrt(dt)*dwr
        float up   = fmaf(znew, 0.1f, f);              // u*sqrt(2) = f + 0.1*z_new
        kld = fmaf(up * up, qc, kld);                  // += dt*0.5*u^2

        zp[(size_t)k * n] = znew;                      // z_t[k+1]
        z   = znew;
        dwr = dwr_next;
    }

    out[(size_t)NT * n + i] = kld;                     // kldiv
}

extern "C" void kernel_launch(void* const* d_in, const int* in_sizes, int n_in,
                              void* d_out, int out_size, void* d_ws, size_t ws_size,
                              hipStream_t stream) {
    const float* z0 = (const float*)d_in[0];
    const float* dW = (const float*)d_in[1];
    const float* W1 = (const float*)d_in[2];
    const float* b1 = (const float*)d_in[3];
    const float* wt = (const float*)d_in[4];
    const float* W2 = (const float*)d_in[5];
    const float* b2 = (const float*)d_in[6];
    int n = in_sizes[0];

    int blocks = (n + 255) / 256;
    sde_kernel<<<blocks, 256, 0, stream>>>(z0, dW, W1, b1, wt, W2, b2,
                                           (float*)d_out, n);
}

// Round 2
// 57.495 us; speedup vs baseline: 1.1297x; 1.1297x over previous
//
#include <hip/hip_runtime.h>

#define NT 100
#define NSTEPS 99

static __device__ __forceinline__ float fast_exp2(float x) {
#if __has_builtin(__builtin_amdgcn_exp2f)
    return __builtin_amdgcn_exp2f(x);
#else
    return exp2f(x);
#endif
}
static __device__ __forceinline__ float fast_rcp(float x) {
#if __has_builtin(__builtin_amdgcn_rcpf)
    return __builtin_amdgcn_rcpf(x);
#else
    return 1.0f / x;
#endif
}

// One thread = one sample; serial loop over the 99 EM steps, software-pipelined
// depth-4 on the dW loads. out layout: z_t [100*n] floats, then kld [n] floats.
__global__ __launch_bounds__(256, 4)
void sde_kernel(const float* __restrict__ z0_raw,
                const float* __restrict__ dW_raw,
                const float* __restrict__ W1,
                const float* __restrict__ b1,
                const float* __restrict__ wt,
                const float* __restrict__ W2,
                const float* __restrict__ b2,
                float* __restrict__ out,
                int n)
{
    int i = blockIdx.x * blockDim.x + threadIdx.x;
    if (i >= n) return;

    // Pre-scale weights by K = 2*log2(e) so tanh(x) = 1 - 2*rcp(1 + exp2(x*K))
    const float K = 2.88539008177792681f;
    float aK[8], wtK[8], b1K[8], mW2[8];
    float S = b2[0];
#pragma unroll
    for (int j = 0; j < 8; ++j) {
        aK[j]  = W1[j] * K;
        wtK[j] = wt[j] * K;
        b1K[j] = b1[j] * K;
        float w = W2[j];
        S += w;               // f = S + sum_j r_j * (-2*W2_j), with r_j = rcp(1+e^{2x})
        mW2[j] = -2.0f * w;
    }

    const float dt  = 3.0f / 99.0f;                 // linspace(0,3,100) step (uniform to ulp)
    const float csq = 0.24618298195866545f;         // sqrt(2)*sqrt(dt) = sqrt(2*dt)
    const float qc  = 0.25f * dt;                   // dt*0.5 * (1/2 from u = u'/sqrt(2))

    float z   = z0_raw[i] * 3.0f;
    float kld = 0.0f;
    out[i] = z;                                     // z_t[0]

    const float* dwp = dW_raw + i;
    float*       zp  = out + (size_t)n + i;

    // one EM step: consumes dW for step k, writes z_t[k+1]
    auto step = [&](int k, float dwr) {
        float t0   = (float)k * dt;
        float acc0 = S;
        float acc1 = 0.0f;
#pragma unroll
        for (int j = 0; j < 4; ++j) {
            float preA = fmaf(z, aK[j],     fmaf(t0, wtK[j],     b1K[j]));
            float preB = fmaf(z, aK[j + 4], fmaf(t0, wtK[j + 4], b1K[j + 4]));
            float rA   = fast_rcp(fast_exp2(preA) + 1.0f);
            float rB   = fast_rcp(fast_exp2(preB) + 1.0f);
            acc0 = fmaf(rA, mW2[j],     acc0);
            acc1 = fmaf(rB, mW2[j + 4], acc1);
        }
        float f    = acc0 + acc1;
        float znew = fmaf(dwr, csq, fmaf(f, dt, z));   // z + f*dt + sqrt(2*dt)*dwr
        float up   = fmaf(znew, 0.1f, f);              // u*sqrt(2) = f + 0.1*z_new
        kld = fmaf(up * up, qc, kld);                  // += dt*0.5*u^2
        zp[(size_t)k * n] = znew;                      // z_t[k+1]
        z = znew;
    };

    // prime the 4-deep register queue with steps 0..3
    float dw0 = dwp[0];
    float dw1 = dwp[(size_t)1 * n];
    float dw2 = dwp[(size_t)2 * n];
    float dw3 = dwp[(size_t)3 * n];

    // main loop: 24 iterations x 4 steps = steps 0..95
    for (int kb = 0; kb < 96; kb += 4) {
        // issue next 4 loads first (clamped at the tail; redundant re-reads hit L1)
        int p0 = min(kb + 4, NSTEPS - 1);
        int p1 = min(kb + 5, NSTEPS - 1);
        int p2 = min(kb + 6, NSTEPS - 1);
        int p3 = min(kb + 7, NSTEPS - 1);
        float n0 = dwp[(size_t)p0 * n];
        float n1 = dwp[(size_t)p1 * n];
        float n2 = dwp[(size_t)p2 * n];
        float n3 = dwp[(size_t)p3 * n];

        step(kb + 0, dw0);
        step(kb + 1, dw1);
        step(kb + 2, dw2);
        step(kb + 3, dw3);

        dw0 = n0; dw1 = n1; dw2 = n2; dw3 = n3;
    }
    // tail: steps 96, 97, 98
    step(96, dw0);
    step(97, dw1);
    step(98, dw2);

    out[(size_t)NT * n + i] = kld;                     // kldiv
}

extern "C" void kernel_launch(void* const* d_in, const int* in_sizes, int n_in,
                              void* d_out, int out_size, void* d_ws, size_t ws_size,
                              hipStream_t stream) {
    const float* z0 = (const float*)d_in[0];
    const float* dW = (const float*)d_in[1];
    const float* W1 = (const float*)d_in[2];
    const float* b1 = (const float*)d_in[3];
    const float* wt = (const float*)d_in[4];
    const float* W2 = (const float*)d_in[5];
    const float* b2 = (const float*)d_in[6];
    int n = in_sizes[0];

    int blocks = (n + 255) / 256;
    sde_kernel<<<blocks, 256, 0, stream>>>(z0, dW, W1, b1, wt, W2, b2,
                                           (float*)d_out, n);
}

// Round 3
// 50.707 us; speedup vs baseline: 1.2810x; 1.1339x over previous
//
#include <hip/hip_runtime.h>

#define NT 100
#define NSTEPS 99
#define NE 352                      // table nodes per step
#define TAB (NSTEPS * NE)           // 34848 floats = 139392 B LDS
#define ZLO -24.0f
#define ZHI 24.0f

// ---------------------------------------------------------------------------
// Kernel 1: build f(t_k, z_idx) table in global scratch (full precision tanhf).
// f(t,z) = b2 + sum_j W2_j * tanh(W1_j*z + wt_j*t + b1_j)
// ---------------------------------------------------------------------------
__global__ void build_table(const float* __restrict__ W1,
                            const float* __restrict__ b1,
                            const float* __restrict__ wt,
                            const float* __restrict__ W2,
                            const float* __restrict__ b2,
                            float* __restrict__ gt)
{
    int e = blockIdx.x * blockDim.x + threadIdx.x;
    if (e >= TAB) return;
    int k   = e / NE;
    int idx = e - k * NE;
    const float dt = 3.0f / 99.0f;
    const float h  = (ZHI - ZLO) / (float)(NE - 1);
    float t0 = (float)k * dt;
    float z  = ZLO + (float)idx * h;
    float f  = b2[0];
#pragma unroll
    for (int j = 0; j < 8; ++j)
        f += W2[j] * tanhf(fmaf(z, W1[j], fmaf(t0, wt[j], b1[j])));
    gt[e] = f;
}

// ---------------------------------------------------------------------------
// Kernel 2: EM scan. One thread = one sample. Drift MLP replaced by LDS
// piecewise-linear table lookup (zero transcendentals in hot loop).
// BUILD=1 fallback builds the table in-block (if d_ws is too small).
// out layout: z_t [100*n] floats, then kld [n] floats.
// ---------------------------------------------------------------------------
template <int BUILD>
__global__ __launch_bounds__(1024, 4)
void sde_table(const float* __restrict__ z0_raw,
               const float* __restrict__ dW_raw,
               const float* __restrict__ gt,
               const float* __restrict__ W1,
               const float* __restrict__ b1,
               const float* __restrict__ wt,
               const float* __restrict__ W2,
               const float* __restrict__ b2,
               float* __restrict__ out,
               int n)
{
    extern __shared__ float tb[];
    const int tid = threadIdx.x;
    const float dt = 3.0f / 99.0f;
    const float h  = (ZHI - ZLO) / (float)(NE - 1);

    if (BUILD) {
        float w1l[8], b1l[8], wtl[8], w2l[8];
        float bb = b2[0];
#pragma unroll
        for (int j = 0; j < 8; ++j) {
            w1l[j] = W1[j]; b1l[j] = b1[j]; wtl[j] = wt[j]; w2l[j] = W2[j];
        }
        for (int e = tid; e < TAB; e += blockDim.x) {
            int k   = e / NE;
            int idx = e - k * NE;
            float t0 = (float)k * dt;
            float z  = ZLO + (float)idx * h;
            float f  = bb;
#pragma unroll
            for (int j = 0; j < 8; ++j)
                f += w2l[j] * tanhf(fmaf(z, w1l[j], fmaf(t0, wtl[j], b1l[j])));
            tb[e] = f;
        }
    } else {
        for (int e = tid; e < TAB; e += blockDim.x) tb[e] = gt[e];
    }
    __syncthreads();

    int i = blockIdx.x * blockDim.x + tid;
    if (i >= n) return;

    const float INVH = (float)(NE - 1) / (ZHI - ZLO);
    const float csq  = 0.24618298195866545f;   // sqrt(2*dt)
    const float qc   = 0.25f * dt;             // dt*0.5 * (1/2 from u = u'/sqrt2)

    float z   = z0_raw[i] * 3.0f;
    float kld = 0.0f;
    out[i] = z;                                // z_t[0]

    const float* dwp = dW_raw + i;
    float*       zp  = out + (size_t)n + i;

    auto step = [&](int k, float dwr) {
        const float* tbk = tb + k * NE;
        float zc   = fminf(fmaxf(z, ZLO), ZHI);        // constant extrapolation
        float u    = (zc - ZLO) * INVH;
        int   iu   = (int)u;
        iu = iu > (NE - 2) ? (NE - 2) : iu;
        float frac = u - (float)iu;
        float f0   = tbk[iu];
        float f1   = tbk[iu + 1];
        float f    = fmaf(frac, f1 - f0, f0);
        float znew = fmaf(dwr, csq, fmaf(f, dt, z));   // z + f*dt + sqrt(2dt)*dW
        float up   = fmaf(znew, 0.1f, f);              // u*sqrt(2)
        kld = fmaf(up * up, qc, kld);
        zp[(size_t)k * n] = znew;                      // z_t[k+1]
        z = znew;
    };

    // depth-8 software pipeline on the dW loads
    float q0 = dwp[0];
    float q1 = dwp[(size_t)1 * n];
    float q2 = dwp[(size_t)2 * n];
    float q3 = dwp[(size_t)3 * n];
    float q4 = dwp[(size_t)4 * n];
    float q5 = dwp[(size_t)5 * n];
    float q6 = dwp[(size_t)6 * n];
    float q7 = dwp[(size_t)7 * n];

    for (int kb = 0; kb < 96; kb += 8) {
        int p0 = min(kb + 8,  NSTEPS - 1);
        int p1 = min(kb + 9,  NSTEPS - 1);
        int p2 = min(kb + 10, NSTEPS - 1);
        int p3 = min(kb + 11, NSTEPS - 1);
        int p4 = min(kb + 12, NSTEPS - 1);
        int p5 = min(kb + 13, NSTEPS - 1);
        int p6 = min(kb + 14, NSTEPS - 1);
        int p7 = min(kb + 15, NSTEPS - 1);
        float n0 = dwp[(size_t)p0 * n];
        float n1 = dwp[(size_t)p1 * n];
        float n2 = dwp[(size_t)p2 * n];
        float n3 = dwp[(size_t)p3 * n];
        float n4 = dwp[(size_t)p4 * n];
        float n5 = dwp[(size_t)p5 * n];
        float n6 = dwp[(size_t)p6 * n];
        float n7 = dwp[(size_t)p7 * n];

        step(kb + 0, q0); step(kb + 1, q1); step(kb + 2, q2); step(kb + 3, q3);
        step(kb + 4, q4); step(kb + 5, q5); step(kb + 6, q6); step(kb + 7, q7);

        q0 = n0; q1 = n1; q2 = n2; q3 = n3;
        q4 = n4; q5 = n5; q6 = n6; q7 = n7;
    }
    // loop computed steps 0..95; queue now holds loads for steps 96,97,98,(98...)
    step(96, q0); step(97, q1); step(98, q2);

    out[(size_t)NT * n + i] = kld;             // kldiv
}

extern "C" void kernel_launch(void* const* d_in, const int* in_sizes, int n_in,
                              void* d_out, int out_size, void* d_ws, size_t ws_size,
                              hipStream_t stream) {
    const float* z0 = (const float*)d_in[0];
    const float* dW = (const float*)d_in[1];
    const float* W1 = (const float*)d_in[2];
    const float* b1 = (const float*)d_in[3];
    const float* wt = (const float*)d_in[4];
    const float* W2 = (const float*)d_in[5];
    const float* b2 = (const float*)d_in[6];
    int n = in_sizes[0];

    const size_t ldsBytes = (size_t)TAB * sizeof(float);   // 139392 B
    int blocks = (n + 1023) / 1024;

    if (ws_size >= ldsBytes) {
        float* gt = (float*)d_ws;
        // allow >64KB dynamic LDS (idempotent host-side call; not a stream op)
        (void)hipFuncSetAttribute((const void*)&sde_table<0>,
                                  hipFuncAttributeMaxDynamicSharedMemorySize,
                                  (int)ldsBytes);
        build_table<<<(TAB + 255) / 256, 256, 0, stream>>>(W1, b1, wt, W2, b2, gt);
        sde_table<0><<<blocks, 1024, ldsBytes, stream>>>(z0, dW, gt, W1, b1, wt,
                                                         W2, b2, (float*)d_out, n);
    } else {
        (void)hipFuncSetAttribute((const void*)&sde_table<1>,
                                  hipFuncAttributeMaxDynamicSharedMemorySize,
                                  (int)ldsBytes);
        sde_table<1><<<blocks, 1024, ldsBytes, stream>>>(z0, dW, (const float*)d_ws,
                                                         W1, b1, wt, W2, b2,
                                                         (float*)d_out, n);
    }
}

// Round 4
// 46.995 us; speedup vs baseline: 1.3821x; 1.0790x over previous
//
#include <hip/hip_runtime.h>

#define NT 100
#define NSTEPS 99
#define NE 352                      // table nodes per step
#define TAB (NSTEPS * NE)           // 34848 floats = 139392 B LDS
#define ZLO -24.0f
#define ZHI 24.0f

// ---------------------------------------------------------------------------
// Kernel 1: build f(t_k, z_idx) table in global scratch (full precision tanhf).
// f(t,z) = b2 + sum_j W2_j * tanh(W1_j*z + wt_j*t + b1_j)
// ---------------------------------------------------------------------------
__global__ void build_table(const float* __restrict__ W1,
                            const float* __restrict__ b1,
                            const float* __restrict__ wt,
                            const float* __restrict__ W2,
                            const float* __restrict__ b2,
                            float* __restrict__ gt)
{
    int e = blockIdx.x * blockDim.x + threadIdx.x;
    if (e >= TAB) return;
    int k   = e / NE;
    int idx = e - k * NE;
    const float dt = 3.0f / 99.0f;
    const float h  = (ZHI - ZLO) / (float)(NE - 1);
    float t0 = (float)k * dt;
    float z  = ZLO + (float)idx * h;
    float f  = b2[0];
#pragma unroll
    for (int j = 0; j < 8; ++j)
        f += W2[j] * tanhf(fmaf(z, W1[j], fmaf(t0, wt[j], b1[j])));
    gt[e] = f;
}

// ---------------------------------------------------------------------------
// Kernel 2: EM scan. One thread = one sample. Drift via LDS linear-interp
// table. Scan phase holds all 99 z values in registers (no stores in the
// load-wait window); epilogue streams them out with nontemporal stores so
// z_t write-back neither couples into vmcnt waits nor evicts dW from L3.
// out layout: z_t [100*n] floats, then kld [n] floats.
// ---------------------------------------------------------------------------
template <int BUILD>
__global__ __launch_bounds__(1024, 4)
void sde_table(const float* __restrict__ z0_raw,
               const float* __restrict__ dW_raw,
               const float* __restrict__ gt,
               const float* __restrict__ W1,
               const float* __restrict__ b1,
               const float* __restrict__ wt,
               const float* __restrict__ W2,
               const float* __restrict__ b2,
               float* __restrict__ out,
               int n)
{
    extern __shared__ float tb[];
    const int tid = threadIdx.x;
    const float dt = 3.0f / 99.0f;

    if (BUILD) {
        const float h = (ZHI - ZLO) / (float)(NE - 1);
        float w1l[8], b1l[8], wtl[8], w2l[8];
        float bb = b2[0];
#pragma unroll
        for (int j = 0; j < 8; ++j) {
            w1l[j] = W1[j]; b1l[j] = b1[j]; wtl[j] = wt[j]; w2l[j] = W2[j];
        }
        for (int e = tid; e < TAB; e += blockDim.x) {
            int k   = e / NE;
            int idx = e - k * NE;
            float t0 = (float)k * dt;
            float z  = ZLO + (float)idx * h;
            float f  = bb;
#pragma unroll
            for (int j = 0; j < 8; ++j)
                f += w2l[j] * tanhf(fmaf(z, w1l[j], fmaf(t0, wtl[j], b1l[j])));
            tb[e] = f;
        }
    } else {
        // vectorized table load: TAB % 4 == 0
        const float4* g4 = (const float4*)gt;
        float4*       t4 = (float4*)tb;
        for (int e = tid; e < TAB / 4; e += blockDim.x) t4[e] = g4[e];
    }
    __syncthreads();

    int i = blockIdx.x * blockDim.x + tid;
    if (i >= n) return;

    const float INVH = (float)(NE - 1) / (ZHI - ZLO);
    const float C0   = -ZLO * INVH;            // u = z*INVH + C0
    const float csq  = 0.24618298195866545f;   // sqrt(2*dt)
    const float qc   = 0.25f * dt;             // dt*0.5 * (1/2 from u = u'/sqrt2)

    float z0  = z0_raw[i] * 3.0f;
    float z   = z0;
    float kld = 0.0f;

    const float* dwp = dW_raw + i;
    float*       zp  = out + (size_t)n + i;

    float zs[NSTEPS];                          // all step outputs, registers only
    float q[8];
#pragma unroll
    for (int k = 0; k < 8; ++k) q[k] = dwp[(size_t)k * n];

#pragma unroll
    for (int k = 0; k < NSTEPS; ++k) {
        float dwr = q[k & 7];
        if (k + 8 < NSTEPS) q[k & 7] = dwp[(size_t)(k + 8) * n];

        const float* tbk = tb + k * NE;
        float u    = fminf(fmaxf(fmaf(z, INVH, C0), 0.0f), 350.999f);
        int   iu   = (int)u;
        float frac = u - (float)iu;
        float f0   = tbk[iu];
        float f1   = tbk[iu + 1];
        float f    = fmaf(frac, f1 - f0, f0);
        float znew = fmaf(dwr, csq, fmaf(f, dt, z));   // z + f*dt + sqrt(2dt)*dW
        float up   = fmaf(znew, 0.1f, f);              // u*sqrt(2)
        kld = fmaf(up * up, qc, kld);
        zs[k] = znew;
        z = znew;
    }

    // epilogue: stream everything out, bypassing L2/L3 (keep dW resident)
    __builtin_nontemporal_store(z0, &out[i]);          // z_t[0]
#pragma unroll
    for (int k = 0; k < NSTEPS; ++k)
        __builtin_nontemporal_store(zs[k], &zp[(size_t)k * n]);
    __builtin_nontemporal_store(kld, &out[(size_t)NT * n + i]);
}

extern "C" void kernel_launch(void* const* d_in, const int* in_sizes, int n_in,
                              void* d_out, int out_size, void* d_ws, size_t ws_size,
                              hipStream_t stream) {
    const float* z0 = (const float*)d_in[0];
    const float* dW = (const float*)d_in[1];
    const float* W1 = (const float*)d_in[2];
    const float* b1 = (const float*)d_in[3];
    const float* wt = (const float*)d_in[4];
    const float* W2 = (const float*)d_in[5];
    const float* b2 = (const float*)d_in[6];
    int n = in_sizes[0];

    const size_t ldsBytes = (size_t)TAB * sizeof(float);   // 139392 B
    int blocks = (n + 1023) / 1024;

    if (ws_size >= ldsBytes) {
        float* gt = (float*)d_ws;
        (void)hipFuncSetAttribute((const void*)&sde_table<0>,
                                  hipFuncAttributeMaxDynamicSharedMemorySize,
                                  (int)ldsBytes);
        build_table<<<(TAB + 255) / 256, 256, 0, stream>>>(W1, b1, wt, W2, b2, gt);
        sde_table<0><<<blocks, 1024, ldsBytes, stream>>>(z0, dW, gt, W1, b1, wt,
                                                         W2, b2, (float*)d_out, n);
    } else {
        (void)hipFuncSetAttribute((const void*)&sde_table<1>,
                                  hipFuncAttributeMaxDynamicSharedMemorySize,
                                  (int)ldsBytes);
        sde_table<1><<<blocks, 1024, ldsBytes, stream>>>(z0, dW, (const float*)d_ws,
                                                         W1, b1, wt, W2, b2,
                                                         (float*)d_out, n);
    }
}

// Round 5
// 45.994 us; speedup vs baseline: 1.4122x; 1.0218x over previous
//
#include <hip/hip_runtime.h>

#define NT 100
#define NSTEPS 99
#define NE 352                      // table nodes per step
#define TAB (NSTEPS * NE)           // 34848 floats = 139392 B LDS
#define ZLO -24.0f
#define ZHI 24.0f
#define CH 16                       // steps per load/compute/store chunk

#define FENCE() asm volatile("" ::: "memory")

// ---------------------------------------------------------------------------
// Kernel 1: build f(t_k, z_idx) table in global scratch (full precision tanhf).
// ---------------------------------------------------------------------------
__global__ void build_table(const float* __restrict__ W1,
                            const float* __restrict__ b1,
                            const float* __restrict__ wt,
                            const float* __restrict__ W2,
                            const float* __restrict__ b2,
                            float* __restrict__ gt)
{
    int e = blockIdx.x * blockDim.x + threadIdx.x;
    if (e >= TAB) return;
    int k   = e / NE;
    int idx = e - k * NE;
    const float dt = 3.0f / 99.0f;
    const float h  = (ZHI - ZLO) / (float)(NE - 1);
    float t0 = (float)k * dt;
    float z  = ZLO + (float)idx * h;
    float f  = b2[0];
#pragma unroll
    for (int j = 0; j < 8; ++j)
        f += W2[j] * tanhf(fmaf(z, W1[j], fmaf(t0, wt[j], b1[j])));
    gt[e] = f;
}

// ---------------------------------------------------------------------------
// Kernel 2: EM scan, phase-fenced chunks of 16 steps:
//   [burst-issue next 16 dW loads] | [16 steps LDS-interp compute] | [16 nt stores]
// Fences pin the phase order so stores cannot be re-sunk between the loads.
// out layout: z_t [100*n] floats, then kld [n] floats.
// ---------------------------------------------------------------------------
template <int BUILD>
__global__ __launch_bounds__(1024, 4)
void sde_table(const float* __restrict__ z0_raw,
               const float* __restrict__ dW_raw,
               const float* __restrict__ gt,
               const float* __restrict__ W1,
               const float* __restrict__ b1,
               const float* __restrict__ wt,
               const float* __restrict__ W2,
               const float* __restrict__ b2,
               float* __restrict__ out,
               int n)
{
    extern __shared__ float tb[];
    const int tid = threadIdx.x;
    const float dt = 3.0f / 99.0f;

    if (BUILD) {
        const float h = (ZHI - ZLO) / (float)(NE - 1);
        float w1l[8], b1l[8], wtl[8], w2l[8];
        float bb = b2[0];
#pragma unroll
        for (int j = 0; j < 8; ++j) {
            w1l[j] = W1[j]; b1l[j] = b1[j]; wtl[j] = wt[j]; w2l[j] = W2[j];
        }
        for (int e = tid; e < TAB; e += blockDim.x) {
            int k   = e / NE;
            int idx = e - k * NE;
            float t0 = (float)k * dt;
            float zz = ZLO + (float)idx * h;
            float f  = bb;
#pragma unroll
            for (int j = 0; j < 8; ++j)
                f += w2l[j] * tanhf(fmaf(zz, w1l[j], fmaf(t0, wtl[j], b1l[j])));
            tb[e] = f;
        }
    } else {
        const float4* g4 = (const float4*)gt;
        float4*       t4 = (float4*)tb;
        for (int e = tid; e < TAB / 4; e += blockDim.x) t4[e] = g4[e];
    }
    __syncthreads();

    int i = blockIdx.x * blockDim.x + tid;
    if (i >= n) return;

    const float INVH = (float)(NE - 1) / (ZHI - ZLO);
    const float C0   = -ZLO * INVH;            // u = z*INVH + C0
    const float csq  = 0.24618298195866545f;   // sqrt(2*dt)
    const float qc   = 0.25f * dt;             // dt*0.5 * (1/2 from u = u'/sqrt2)

    float z0  = z0_raw[i] * 3.0f;
    float z   = z0;
    float kld = 0.0f;

    const float* dwp = dW_raw + i;
    float*       zp  = out + (size_t)n + i;

    // one EM step; returns z_new
    auto stepf = [&](int k, float dwr) -> float {
        const float* tbk = tb + k * NE;
        float u    = fminf(fmaxf(fmaf(z, INVH, C0), 0.0f), 350.999f);
        int   iu   = (int)u;
        float frac = u - (float)iu;
        float f0   = tbk[iu];
        float f1   = tbk[iu + 1];
        float f    = fmaf(frac, f1 - f0, f0);
        float znew = fmaf(dwr, csq, fmaf(f, dt, z));   // z + f*dt + sqrt(2dt)*dW
        float up   = fmaf(znew, 0.1f, f);              // u*sqrt(2)
        kld = fmaf(up * up, qc, kld);
        z = znew;
        return znew;
    };

    float qA[CH], qB[CH], zs[CH];

    // prologue: burst-issue chunk 0 into qA
#pragma unroll
    for (int j = 0; j < CH; ++j) qA[j] = dwp[(size_t)j * n];
    FENCE();

    __builtin_nontemporal_store(z0, &out[i]);          // z_t[0]

    // 6 full chunks cover steps 0..95; tail handles 96..98
#pragma unroll
    for (int c = 0; c < 6; ++c) {
        const int base = c * CH;
        // phase 1: burst-issue next chunk's loads into the other buffer
        if (c & 1) {
#pragma unroll
            for (int j = 0; j < CH; ++j) {
                int k = base + CH + j;
                if (k < NSTEPS) qA[j] = dwp[(size_t)k * n];
            }
        } else {
#pragma unroll
            for (int j = 0; j < CH; ++j) {
                int k = base + CH + j;
                if (k < NSTEPS) qB[j] = dwp[(size_t)k * n];
            }
        }
        FENCE();
        // phase 2: compute 16 steps (LDS + VALU only)
#pragma unroll
        for (int j = 0; j < CH; ++j)
            zs[j] = stepf(base + j, (c & 1) ? qB[j] : qA[j]);
        FENCE();
        // phase 3: burst nt stores
#pragma unroll
        for (int j = 0; j < CH; ++j)
            __builtin_nontemporal_store(zs[j], &zp[(size_t)(base + j) * n]);
        FENCE();
    }

    // tail: steps 96..98 (loaded into qA during chunk c=5)
    float zt0 = stepf(96, qA[0]);
    float zt1 = stepf(97, qA[1]);
    float zt2 = stepf(98, qA[2]);
    FENCE();
    __builtin_nontemporal_store(zt0, &zp[(size_t)96 * n]);
    __builtin_nontemporal_store(zt1, &zp[(size_t)97 * n]);
    __builtin_nontemporal_store(zt2, &zp[(size_t)98 * n]);
    __builtin_nontemporal_store(kld, &out[(size_t)NT * n + i]);
}

extern "C" void kernel_launch(void* const* d_in, const int* in_sizes, int n_in,
                              void* d_out, int out_size, void* d_ws, size_t ws_size,
                              hipStream_t stream) {
    const float* z0 = (const float*)d_in[0];
    const float* dW = (const float*)d_in[1];
    const float* W1 = (const float*)d_in[2];
    const float* b1 = (const float*)d_in[3];
    const float* wt = (const float*)d_in[4];
    const float* W2 = (const float*)d_in[5];
    const float* b2 = (const float*)d_in[6];
    int n = in_sizes[0];

    const size_t ldsBytes = (size_t)TAB * sizeof(float);   // 139392 B
    int blocks = (n + 1023) / 1024;

    if (ws_size >= ldsBytes) {
        float* gt = (float*)d_ws;
        (void)hipFuncSetAttribute((const void*)&sde_table<0>,
                                  hipFuncAttributeMaxDynamicSharedMemorySize,
                                  (int)ldsBytes);
        build_table<<<(TAB + 255) / 256, 256, 0, stream>>>(W1, b1, wt, W2, b2, gt);
        sde_table<0><<<blocks, 1024, ldsBytes, stream>>>(z0, dW, gt, W1, b1, wt,
                                                         W2, b2, (float*)d_out, n);
    } else {
        (void)hipFuncSetAttribute((const void*)&sde_table<1>,
                                  hipFuncAttributeMaxDynamicSharedMemorySize,
                                  (int)ldsBytes);
        sde_table<1><<<blocks, 1024, ldsBytes, stream>>>(z0, dW, (const float*)d_ws,
                                                         W1, b1, wt, W2, b2,
                                                         (float*)d_out, n);
    }
}

// Round 7
// 45.443 us; speedup vs baseline: 1.4294x; 1.0121x over previous
//
#include <hip/hip_runtime.h>

#define NT 100
#define NSTEPS 99
#define NE 352                      // table nodes per step
#define TAB (NSTEPS * NE)           // 34848 floats = 139392 B LDS
#define ZLO -24.0f
#define ZHI 24.0f

// ---------------------------------------------------------------------------
// Kernel 1: build f(t_k, z_idx) table in global scratch (full precision tanhf).
// ---------------------------------------------------------------------------
__global__ void build_table(const float* __restrict__ W1,
                            const float* __restrict__ b1,
                            const float* __restrict__ wt,
                            const float* __restrict__ W2,
                            const float* __restrict__ b2,
                            float* __restrict__ gt)
{
    int e = blockIdx.x * blockDim.x + threadIdx.x;
    if (e >= TAB) return;
    int k   = e / NE;
    int idx = e - k * NE;
    const float dt = 3.0f / 99.0f;
    const float h  = (ZHI - ZLO) / (float)(NE - 1);
    float t0 = (float)k * dt;
    float z  = ZLO + (float)idx * h;
    float f  = b2[0];
#pragma unroll
    for (int j = 0; j < 8; ++j)
        f += W2[j] * tanhf(fmaf(z, W1[j], fmaf(t0, wt[j], b1[j])));
    gt[e] = f;
}

// ---------------------------------------------------------------------------
// Kernel 2: EM scan with a compiler-proof software pipeline (macro-expanded,
// named registers — no arrays/lambdas in asm operands).
//   - 24-deep inline-asm global_load ring (32 named floats, SSA-collapsed)
//   - exact literal s_waitcnt vmcnt(N) per step (loads+stores both counted,
//     in-order decrement; stores clear early so they never gate for long)
//   - inline-asm nt stores
// out layout: z_t [100*n] floats, then kld [n] floats.
// ---------------------------------------------------------------------------

__device__ __forceinline__ float em_step(int k, float dwr, float& z, float& kld,
                                         const float* tb, float INVH, float C0,
                                         float csq, float qc, float dt)
{
    const float* tbk = tb + k * NE;
    float u    = fminf(fmaxf(fmaf(z, INVH, C0), 0.0f), 350.999f);
    int   iu   = (int)u;
    float frac = u - (float)iu;
    float f0   = tbk[iu];
    float f1   = tbk[iu + 1];
    float f    = fmaf(frac, f1 - f0, f0);
    float znew = fmaf(dwr, csq, fmaf(f, dt, z));   // z + f*dt + sqrt(2dt)*dW
    float up   = fmaf(znew, 0.1f, f);              // u*sqrt(2)
    kld = fmaf(up * up, qc, kld);
    z = znew;
    return znew;
}

#define LOADK(K, REG) { const float* p_ = dwp + (size_t)(K) * n;               \
    asm volatile("global_load_dword %0, %1, off" : "=v"(REG) : "v"(p_)); }

#define STOREK(K, VAL) { float* p_ = zp + (size_t)(K) * n;                     \
    asm volatile("global_store_dword %0, %1, off nt" :: "v"(p_), "v"(VAL)); }

// steady/step with prefetch: load L(K+24) into WR, wait, compute, store
#define STEPL(K, CONS, WR, NW)                                                 \
    LOADK((K) + 24, WR);                                                       \
    asm volatile("s_waitcnt vmcnt(%1)" : "+v"(CONS) : "n"(NW));                \
    { float zn_ = em_step((K), CONS, z, kld, tb, INVH, C0, csq, qc, dt);       \
      STOREK((K), zn_); }

// tail step, no prefetch
#define STEPN(K, CONS, NW)                                                     \
    asm volatile("s_waitcnt vmcnt(%1)" : "+v"(CONS) : "n"(NW));                \
    { float zn_ = em_step((K), CONS, z, kld, tb, INVH, C0, csq, qc, dt);       \
      STOREK((K), zn_); }

template <int BUILD>
__global__ __launch_bounds__(1024, 4)
void sde_pipe(const float* __restrict__ z0_raw,
              const float* __restrict__ dW_raw,
              const float* __restrict__ gt,
              const float* __restrict__ W1,
              const float* __restrict__ b1,
              const float* __restrict__ wt,
              const float* __restrict__ W2,
              const float* __restrict__ b2,
              float* __restrict__ out,
              int n)
{
    extern __shared__ float tb[];
    const int tid = threadIdx.x;
    const float dt = 3.0f / 99.0f;

    if (BUILD) {
        const float h = (ZHI - ZLO) / (float)(NE - 1);
        float w1l[8], b1l[8], wtl[8], w2l[8];
        float bb = b2[0];
#pragma unroll
        for (int j = 0; j < 8; ++j) {
            w1l[j] = W1[j]; b1l[j] = b1[j]; wtl[j] = wt[j]; w2l[j] = W2[j];
        }
        for (int e = tid; e < TAB; e += blockDim.x) {
            int k   = e / NE;
            int idx = e - k * NE;
            float t0 = (float)k * dt;
            float zz = ZLO + (float)idx * h;
            float f  = bb;
#pragma unroll
            for (int j = 0; j < 8; ++j)
                f += w2l[j] * tanhf(fmaf(zz, w1l[j], fmaf(t0, wtl[j], b1l[j])));
            tb[e] = f;
        }
    } else {
        const float4* g4 = (const float4*)gt;
        float4*       t4 = (float4*)tb;
        for (int e = tid; e < TAB / 4; e += blockDim.x) t4[e] = g4[e];
    }
    __syncthreads();   // all prior vmem drained here -> clean vmcnt slate

    int i = blockIdx.x * blockDim.x + tid;
    if (i >= n) return;

    const float INVH = (float)(NE - 1) / (ZHI - ZLO);
    const float C0   = -ZLO * INVH;            // u = z*INVH + C0
    const float csq  = 0.24618298195866545f;   // sqrt(2*dt)
    const float qc   = 0.25f * dt;             // dt*0.5 * (1/2 from u = u'/sqrt2)

    float z0v = z0_raw[i] * 3.0f;
    float z   = z0v;
    float kld = 0.0f;

    const float* dwp = dW_raw + i;
    float*       zp  = out + (size_t)n + i;

    // force the z0 load to be waited on BEFORE the counted region starts
    asm volatile("" : "+v"(z), "+v"(z0v));

    float r0,r1,r2,r3,r4,r5,r6,r7,r8,r9,r10,r11,r12,r13,r14,r15,
          r16,r17,r18,r19,r20,r21,r22,r23,r24,r25,r26,r27,r28,r29,r30,r31;

    // prologue: burst-issue loads for steps 0..23
    LOADK(0,  r0);  LOADK(1,  r1);  LOADK(2,  r2);  LOADK(3,  r3);
    LOADK(4,  r4);  LOADK(5,  r5);  LOADK(6,  r6);  LOADK(7,  r7);
    LOADK(8,  r8);  LOADK(9,  r9);  LOADK(10, r10); LOADK(11, r11);
    LOADK(12, r12); LOADK(13, r13); LOADK(14, r14); LOADK(15, r15);
    LOADK(16, r16); LOADK(17, r17); LOADK(18, r18); LOADK(19, r19);
    LOADK(20, r20); LOADK(21, r21); LOADK(22, r22); LOADK(23, r23);

    STEPL(0,  r0,  r24, 24) STEPL(1,  r1,  r25, 25) STEPL(2,  r2,  r26, 26)
    STEPL(3,  r3,  r27, 27) STEPL(4,  r4,  r28, 28) STEPL(5,  r5,  r29, 29)
    STEPL(6,  r6,  r30, 30) STEPL(7,  r7,  r31, 31) STEPL(8,  r8,  r0,  32)
    STEPL(9,  r9,  r1,  33) STEPL(10, r10, r2,  34) STEPL(11, r11, r3,  35)
    STEPL(12, r12, r4,  36) STEPL(13, r13, r5,  37) STEPL(14, r14, r6,  38)
    STEPL(15, r15, r7,  39) STEPL(16, r16, r8,  40) STEPL(17, r17, r9,  41)
    STEPL(18, r18, r10, 42) STEPL(19, r19, r11, 43) STEPL(20, r20, r12, 44)
    STEPL(21, r21, r13, 45) STEPL(22, r22, r14, 46) STEPL(23, r23, r15, 47)
    STEPL(24, r24, r16, 48) STEPL(25, r25, r17, 48) STEPL(26, r26, r18, 48)
    STEPL(27, r27, r19, 48) STEPL(28, r28, r20, 48) STEPL(29, r29, r21, 48)
    STEPL(30, r30, r22, 48) STEPL(31, r31, r23, 48) STEPL(32, r0,  r24, 48)
    STEPL(33, r1,  r25, 48) STEPL(34, r2,  r26, 48) STEPL(35, r3,  r27, 48)
    STEPL(36, r4,  r28, 48) STEPL(37, r5,  r29, 48) STEPL(38, r6,  r30, 48)
    STEPL(39, r7,  r31, 48) STEPL(40, r8,  r0,  48) STEPL(41, r9,  r1,  48)
    STEPL(42, r10, r2,  48) STEPL(43, r11, r3,  48) STEPL(44, r12, r4,  48)
    STEPL(45, r13, r5,  48) STEPL(46, r14, r6,  48) STEPL(47, r15, r7,  48)
    STEPL(48, r16, r8,  48) STEPL(49, r17, r9,  48) STEPL(50, r18, r10, 48)
    STEPL(51, r19, r11, 48) STEPL(52, r20, r12, 48) STEPL(53, r21, r13, 48)
    STEPL(54, r22, r14, 48) STEPL(55, r23, r15, 48) STEPL(56, r24, r16, 48)
    STEPL(57, r25, r17, 48) STEPL(58, r26, r18, 48) STEPL(59, r27, r19, 48)
    STEPL(60, r28, r20, 48) STEPL(61, r29, r21, 48) STEPL(62, r30, r22, 48)
    STEPL(63, r31, r23, 48) STEPL(64, r0,  r24, 48) STEPL(65, r1,  r25, 48)
    STEPL(66, r2,  r26, 48) STEPL(67, r3,  r27, 48) STEPL(68, r4,  r28, 48)
    STEPL(69, r5,  r29, 48) STEPL(70, r6,  r30, 48) STEPL(71, r7,  r31, 48)
    STEPL(72, r8,  r0,  48) STEPL(73, r9,  r1,  48) STEPL(74, r10, r2,  48)
    STEPN(75, r11, 47) STEPN(76, r12, 46) STEPN(77, r13, 45)
    STEPN(78, r14, 44) STEPN(79, r15, 43) STEPN(80, r16, 42)
    STEPN(81, r17, 41) STEPN(82, r18, 40) STEPN(83, r19, 39)
    STEPN(84, r20, 38) STEPN(85, r21, 37) STEPN(86, r22, 36)
    STEPN(87, r23, 35) STEPN(88, r24, 34) STEPN(89, r25, 33)
    STEPN(90, r26, 32) STEPN(91, r27, 31) STEPN(92, r28, 30)
    STEPN(93, r29, 29) STEPN(94, r30, 28) STEPN(95, r31, 27)
    STEPN(96, r0,  26) STEPN(97, r1,  25) STEPN(98, r2,  24)

    // drain our asm stores (compiler doesn't track them)
    asm volatile("s_waitcnt vmcnt(0)");

    __builtin_nontemporal_store(z0v, &out[i]);         // z_t[0]
    __builtin_nontemporal_store(kld, &out[(size_t)NT * n + i]);
}

extern "C" void kernel_launch(void* const* d_in, const int* in_sizes, int n_in,
                              void* d_out, int out_size, void* d_ws, size_t ws_size,
                              hipStream_t stream) {
    const float* z0 = (const float*)d_in[0];
    const float* dW = (const float*)d_in[1];
    const float* W1 = (const float*)d_in[2];
    const float* b1 = (const float*)d_in[3];
    const float* wt = (const float*)d_in[4];
    const float* W2 = (const float*)d_in[5];
    const float* b2 = (const float*)d_in[6];
    int n = in_sizes[0];

    const size_t ldsBytes = (size_t)TAB * sizeof(float);   // 139392 B
    int blocks = (n + 1023) / 1024;

    if (ws_size >= ldsBytes) {
        float* gt = (float*)d_ws;
        (void)hipFuncSetAttribute((const void*)&sde_pipe<0>,
                                  hipFuncAttributeMaxDynamicSharedMemorySize,
                                  (int)ldsBytes);
        build_table<<<(TAB + 255) / 256, 256, 0, stream>>>(W1, b1, wt, W2, b2, gt);
        sde_pipe<0><<<blocks, 1024, ldsBytes, stream>>>(z0, dW, gt, W1, b1, wt,
                                                        W2, b2, (float*)d_out, n);
    } else {
        (void)hipFuncSetAttribute((const void*)&sde_pipe<1>,
                                  hipFuncAttributeMaxDynamicSharedMemorySize,
                                  (int)ldsBytes);
        sde_pipe<1><<<blocks, 1024, ldsBytes, stream>>>(z0, dW, (const float*)d_ws,
                                                        W1, b1, wt, W2, b2,
                                                        (float*)d_out, n);
    }
}